// Round 2
// baseline (324.917 us; speedup 1.0000x reference)
//
#include <hip/hip_runtime.h>
#include <math.h>

// CombinedLoss: 0.5 * dice_loss + 0.5 * CE over [B=8, C=23, H=512, W=512] f32 logits.
// Memory-bound: one fused pass over predictions (193 MB) + targets (8 MB).
// Each thread handles 4 consecutive pixels via float4 loads (16 B/lane sweet spot).

#define NC 23
#define HWQ 65536                  // HW/4 in float4 units (HW = 512*512 = 262144)
#define NPIX (8 * 262144)          // 2^21 pixels
#define NQUADS (NPIX / 4)          // 524288 quads
#define NB 2048                    // blocks: NQUADS / 256
#define NQ 47                      // inter[23] + denom[23] + ce

__device__ __forceinline__ float wave_red(float v) {
#pragma unroll
    for (int off = 32; off > 0; off >>= 1) v += __shfl_down(v, off, 64);
    return v;
}

// Process one pixel component (field F of the float4 quad / TF of the int4 targets).
#define PROC_COMP(F, TF)                                                      \
    do {                                                                      \
        float m = l[0].F;                                                     \
        _Pragma("unroll") for (int c = 1; c < NC; ++c) m = fmaxf(m, l[c].F);  \
        int t = t4.TF;                                                        \
        float s = 0.0f, lt = l[0].F;                                          \
        _Pragma("unroll") for (int c = 0; c < NC; ++c) {                      \
            lt = (c == t) ? l[c].F : lt;                                      \
            float e = __expf(l[c].F - m);                                     \
            l[c].F = e;                                                       \
            s += e;                                                           \
        }                                                                     \
        float rinv = __builtin_amdgcn_rcpf(s);                                \
        ce += m + __logf(s) - lt;                                             \
        _Pragma("unroll") for (int c = 0; c < NC; ++c) {                      \
            float pc = l[c].F * rinv;                                         \
            bool is_t = (c == t);                                             \
            inter[c] += is_t ? pc : 0.0f;                                     \
            denom[c] += pc + (is_t ? 1.0f : 0.0f);                            \
        }                                                                     \
    } while (0)

__global__ __launch_bounds__(256) void cl_main(const float4* __restrict__ pred4,
                                               const int4* __restrict__ tgt4,
                                               float* __restrict__ partials) {
    float inter[NC], denom[NC];
#pragma unroll
    for (int c = 0; c < NC; ++c) { inter[c] = 0.0f; denom[c] = 0.0f; }
    float ce = 0.0f;

    int tid = blockIdx.x * blockDim.x + threadIdx.x;   // quad index, exact grid
    int b = tid >> 16;                                 // (4*tid) / HW
    int hwq = tid & (HWQ - 1);                         // quad-of-hw within image
    const float4* base = pred4 + (size_t)b * (NC * HWQ) + hwq;

    float4 l[NC];
#pragma unroll
    for (int c = 0; c < NC; ++c) l[c] = base[c * HWQ];
    int4 t4 = tgt4[tid];

    PROC_COMP(x, x);
    PROC_COMP(y, y);
    PROC_COMP(z, z);
    PROC_COMP(w, w);

    // Block-level reduction of 47 quantities: wave shfl-reduce -> LDS -> partials.
    __shared__ float red[4][NQ + 1];
    int lane = threadIdx.x & 63;
    int wv = threadIdx.x >> 6;

#pragma unroll
    for (int c = 0; c < NC; ++c) {
        float v = wave_red(inter[c]);
        if (lane == 0) red[wv][c] = v;
    }
#pragma unroll
    for (int c = 0; c < NC; ++c) {
        float v = wave_red(denom[c]);
        if (lane == 0) red[wv][NC + c] = v;
    }
    {
        float v = wave_red(ce);
        if (lane == 0) red[wv][2 * NC] = v;
    }
    __syncthreads();

    if (threadIdx.x < NQ) {
        float v = red[0][threadIdx.x] + red[1][threadIdx.x] +
                  red[2][threadIdx.x] + red[3][threadIdx.x];
        partials[(size_t)threadIdx.x * NB + blockIdx.x] = v;
    }
}

__global__ __launch_bounds__(1024) void cl_reduce(const float* __restrict__ partials,
                                                  float* __restrict__ out) {
    __shared__ double res[NQ];
    int lane = threadIdx.x & 63;
    int wv = threadIdx.x >> 6;   // 0..15

    for (int q = wv; q < NQ; q += 16) {
        double acc = 0.0;
        for (int i = lane; i < NB; i += 64) acc += (double)partials[(size_t)q * NB + i];
#pragma unroll
        for (int off = 32; off > 0; off >>= 1) acc += __shfl_down(acc, off, 64);
        if (lane == 0) res[q] = acc;
    }
    __syncthreads();

    if (threadIdx.x == 0) {
        const double S = 1e-5;
        double dice_sum = 0.0;
        for (int c = 0; c < NC; ++c) {
            double dice = (2.0 * res[c] + S) / (res[NC + c] + S);
            dice_sum += (1.0 - dice);
        }
        double dice_loss = dice_sum / (double)NC;
        double ce_mean = res[2 * NC] / (double)NPIX;
        out[0] = (float)(0.5 * dice_loss + 0.5 * ce_mean);
    }
}

extern "C" void kernel_launch(void* const* d_in, const int* in_sizes, int n_in,
                              void* d_out, int out_size, void* d_ws, size_t ws_size,
                              hipStream_t stream) {
    const float4* pred4 = (const float4*)d_in[0];
    const int4* tgt4 = (const int4*)d_in[1];
    float* out = (float*)d_out;
    float* partials = (float*)d_ws;   // NQ * NB floats = 385 KB

    cl_main<<<NB, 256, 0, stream>>>(pred4, tgt4, partials);
    cl_reduce<<<1, 1024, 0, stream>>>(partials, out);
}

// Round 3
// 318.902 us; speedup vs baseline: 1.0189x; 1.0189x over previous
//
#include <hip/hip_runtime.h>
#include <math.h>

// CombinedLoss: 0.5 * dice_loss + 0.5 * CE over [B=8, C=23, H=512, W=512] f32 logits.
// Memory-bound: one fused pass over predictions (193 MB) + targets (8 MB).
// One thread per PIXEL-PAIR (float2 loads, 8 B/lane): keeps the 23-channel live
// range at 46 VGPRs so the allocator fits honestly (round 2's float4 version
// demanded ~150 live and the allocator split the loads -> 137 us, 753 GB/s).

#define NC 23
#define HWP 131072                 // HW/2 in float2 units (HW = 512*512)
#define NPIX (8 * 262144)          // 2^21 pixels
#define NPAIR (NPIX / 2)           // 2^20 pairs
#define NB 4096                    // blocks: NPAIR / 256
#define NQ 47                      // inter[23] + denom[23] + ce

__device__ __forceinline__ float wave_red(float v) {
#pragma unroll
    for (int off = 32; off > 0; off >>= 1) v += __shfl_down(v, off, 64);
    return v;
}

// Process one pixel (component F of the float2 pair / TF of the int2 targets).
#define PROC_COMP(F, TF)                                                      \
    do {                                                                      \
        float m = l[0].F;                                                     \
        _Pragma("unroll") for (int c = 1; c < NC; ++c) m = fmaxf(m, l[c].F);  \
        int t = t2.TF;                                                        \
        float s = 0.0f, lt = l[0].F;                                          \
        float e[NC];                                                          \
        _Pragma("unroll") for (int c = 0; c < NC; ++c) {                      \
            lt = (c == t) ? l[c].F : lt;                                      \
            e[c] = __expf(l[c].F - m);                                        \
            s += e[c];                                                        \
        }                                                                     \
        float rinv = __builtin_amdgcn_rcpf(s);                                \
        ce += m + __logf(s) - lt;                                             \
        _Pragma("unroll") for (int c = 0; c < NC; ++c) {                      \
            float pc = e[c] * rinv;                                           \
            bool is_t = (c == t);                                             \
            inter[c] += is_t ? pc : 0.0f;                                     \
            denom[c] += pc + (is_t ? 1.0f : 0.0f);                            \
        }                                                                     \
    } while (0)

__global__ __launch_bounds__(256, 2) void cl_main(const float2* __restrict__ pred2,
                                                  const int2* __restrict__ tgt2,
                                                  float* __restrict__ partials) {
    float inter[NC], denom[NC];
#pragma unroll
    for (int c = 0; c < NC; ++c) { inter[c] = 0.0f; denom[c] = 0.0f; }
    float ce = 0.0f;

    int tid = blockIdx.x * blockDim.x + threadIdx.x;   // pair index, exact grid
    int b = tid >> 17;                                 // pair / HWP
    int hwp = tid & (HWP - 1);                         // pair within image
    const float2* base = pred2 + (size_t)b * (NC * HWP) + hwp;

    float2 l[NC];
#pragma unroll
    for (int c = 0; c < NC; ++c) l[c] = base[c * HWP];
    int2 t2 = tgt2[tid];

    PROC_COMP(x, x);
    PROC_COMP(y, y);

    // Block-level reduction of 47 quantities: wave shfl-reduce -> LDS -> partials.
    __shared__ float red[4][NQ + 1];
    int lane = threadIdx.x & 63;
    int wv = threadIdx.x >> 6;

#pragma unroll
    for (int c = 0; c < NC; ++c) {
        float v = wave_red(inter[c]);
        if (lane == 0) red[wv][c] = v;
    }
#pragma unroll
    for (int c = 0; c < NC; ++c) {
        float v = wave_red(denom[c]);
        if (lane == 0) red[wv][NC + c] = v;
    }
    {
        float v = wave_red(ce);
        if (lane == 0) red[wv][2 * NC] = v;
    }
    __syncthreads();

    if (threadIdx.x < NQ) {
        float v = red[0][threadIdx.x] + red[1][threadIdx.x] +
                  red[2][threadIdx.x] + red[3][threadIdx.x];
        partials[(size_t)threadIdx.x * NB + blockIdx.x] = v;
    }
}

__global__ __launch_bounds__(1024) void cl_reduce(const float* __restrict__ partials,
                                                  float* __restrict__ out) {
    __shared__ double res[NQ];
    int lane = threadIdx.x & 63;
    int wv = threadIdx.x >> 6;   // 0..15

    for (int q = wv; q < NQ; q += 16) {
        double acc = 0.0;
        for (int i = lane; i < NB; i += 64) acc += (double)partials[(size_t)q * NB + i];
#pragma unroll
        for (int off = 32; off > 0; off >>= 1) acc += __shfl_down(acc, off, 64);
        if (lane == 0) res[q] = acc;
    }
    __syncthreads();

    if (threadIdx.x == 0) {
        const double S = 1e-5;
        double dice_sum = 0.0;
        for (int c = 0; c < NC; ++c) {
            double dice = (2.0 * res[c] + S) / (res[NC + c] + S);
            dice_sum += (1.0 - dice);
        }
        double dice_loss = dice_sum / (double)NC;
        double ce_mean = res[2 * NC] / (double)NPIX;
        out[0] = (float)(0.5 * dice_loss + 0.5 * ce_mean);
    }
}

extern "C" void kernel_launch(void* const* d_in, const int* in_sizes, int n_in,
                              void* d_out, int out_size, void* d_ws, size_t ws_size,
                              hipStream_t stream) {
    const float2* pred2 = (const float2*)d_in[0];
    const int2* tgt2 = (const int2*)d_in[1];
    float* out = (float*)d_out;
    float* partials = (float*)d_ws;   // NQ * NB floats = 770 KB

    cl_main<<<NB, 256, 0, stream>>>(pred2, tgt2, partials);
    cl_reduce<<<1, 1024, 0, stream>>>(partials, out);
}

// Round 4
// 296.986 us; speedup vs baseline: 1.0940x; 1.0738x over previous
//
#include <hip/hip_runtime.h>
#include <math.h>

// CombinedLoss: 0.5 * dice_loss + 0.5 * CE over [B=8, C=23, H=512, W=512] f32 logits.
// One fused pass. float2 per thread-iteration (8 B/lane), 8 pixels/thread so the
// 47-quantity block reduction (~282 cross-lane ops) is amortized (~8% overhead).
// exp() overwrites l[] in place: ~110 live VGPRs -> honest fit, no allocator splits.

#define NC 23
#define HWP 131072                 // HW/2 in float2 units (HW = 512*512)
#define NPIX (8 * 262144)          // 2^21 pixels
#define NPAIR (NPIX / 2)           // 2^20 pairs
#define NB 1024                    // blocks
#define NITER 4                    // pairs per thread: NPAIR / (NB*256)
#define NQ 47                      // inter[23] + denom[23] + ce

__device__ __forceinline__ float wave_red(float v) {
#pragma unroll
    for (int off = 32; off > 0; off >>= 1) v += __shfl_down(v, off, 64);
    return v;
}

// Process one pixel (component F of the float2 pair / TF of the int2 targets).
// exp overwrites l[c].F so no extra temp array is live.
#define PROC_COMP(F, TF)                                                      \
    do {                                                                      \
        float m = l[0].F;                                                     \
        _Pragma("unroll") for (int c = 1; c < NC; ++c) m = fmaxf(m, l[c].F);  \
        int t = t2.TF;                                                        \
        float s = 0.0f, lt = l[0].F;                                          \
        _Pragma("unroll") for (int c = 0; c < NC; ++c) {                      \
            lt = (c == t) ? l[c].F : lt;                                      \
            float e = __expf(l[c].F - m);                                     \
            l[c].F = e;                                                       \
            s += e;                                                           \
        }                                                                     \
        float rinv = __builtin_amdgcn_rcpf(s);                                \
        ce += m + __logf(s) - lt;                                             \
        _Pragma("unroll") for (int c = 0; c < NC; ++c) {                      \
            float pc = l[c].F * rinv;                                         \
            bool is_t = (c == t);                                             \
            inter[c] += is_t ? pc : 0.0f;                                     \
            denom[c] += pc + (is_t ? 1.0f : 0.0f);                            \
        }                                                                     \
    } while (0)

__global__ __launch_bounds__(256, 2) void cl_main(const float2* __restrict__ pred2,
                                                  const int2* __restrict__ tgt2,
                                                  float* __restrict__ partials) {
    float inter[NC], denom[NC];
#pragma unroll
    for (int c = 0; c < NC; ++c) { inter[c] = 0.0f; denom[c] = 0.0f; }
    float ce = 0.0f;

    int tid = blockIdx.x * blockDim.x + threadIdx.x;   // 0 .. NB*256-1
    int hwp = tid & (HWP - 1);                         // pair within image (coalesced)
    int b0 = tid >> 17;                                // 0 or 1

#pragma unroll 1
    for (int it = 0; it < NITER; ++it) {
        int b = (it << 1) | b0;                        // image index 0..7
        const float2* base = pred2 + (size_t)b * (NC * HWP) + hwp;
        int2 t2 = tgt2[((size_t)b << 17) + hwp];

        float2 l[NC];
#pragma unroll
        for (int c = 0; c < NC; ++c) l[c] = base[c * HWP];

        PROC_COMP(x, x);
        PROC_COMP(y, y);
    }

    // Block-level reduction of 47 quantities: wave shfl-reduce -> LDS -> partials.
    __shared__ float red[4][NQ + 1];
    int lane = threadIdx.x & 63;
    int wv = threadIdx.x >> 6;

#pragma unroll
    for (int c = 0; c < NC; ++c) {
        float v = wave_red(inter[c]);
        if (lane == 0) red[wv][c] = v;
    }
#pragma unroll
    for (int c = 0; c < NC; ++c) {
        float v = wave_red(denom[c]);
        if (lane == 0) red[wv][NC + c] = v;
    }
    {
        float v = wave_red(ce);
        if (lane == 0) red[wv][2 * NC] = v;
    }
    __syncthreads();

    if (threadIdx.x < NQ) {
        float v = red[0][threadIdx.x] + red[1][threadIdx.x] +
                  red[2][threadIdx.x] + red[3][threadIdx.x];
        partials[(size_t)threadIdx.x * NB + blockIdx.x] = v;
    }
}

__global__ __launch_bounds__(1024) void cl_reduce(const float* __restrict__ partials,
                                                  float* __restrict__ out) {
    __shared__ double res[NQ];
    int lane = threadIdx.x & 63;
    int wv = threadIdx.x >> 6;   // 0..15

    for (int q = wv; q < NQ; q += 16) {
        double acc = 0.0;
        for (int i = lane; i < NB; i += 64) acc += (double)partials[(size_t)q * NB + i];
#pragma unroll
        for (int off = 32; off > 0; off >>= 1) acc += __shfl_down(acc, off, 64);
        if (lane == 0) res[q] = acc;
    }
    __syncthreads();

    if (threadIdx.x == 0) {
        const double S = 1e-5;
        double dice_sum = 0.0;
        for (int c = 0; c < NC; ++c) {
            double dice = (2.0 * res[c] + S) / (res[NC + c] + S);
            dice_sum += (1.0 - dice);
        }
        double dice_loss = dice_sum / (double)NC;
        double ce_mean = res[2 * NC] / (double)NPIX;
        out[0] = (float)(0.5 * dice_loss + 0.5 * ce_mean);
    }
}

extern "C" void kernel_launch(void* const* d_in, const int* in_sizes, int n_in,
                              void* d_out, int out_size, void* d_ws, size_t ws_size,
                              hipStream_t stream) {
    const float2* pred2 = (const float2*)d_in[0];
    const int2* tgt2 = (const int2*)d_in[1];
    float* out = (float*)d_out;
    float* partials = (float*)d_ws;   // NQ * NB floats = 188 KB

    cl_main<<<NB, 256, 0, stream>>>(pred2, tgt2, partials);
    cl_reduce<<<1, 1024, 0, stream>>>(partials, out);
}

// Round 5
// 289.620 us; speedup vs baseline: 1.1219x; 1.0254x over previous
//
#include <hip/hip_runtime.h>
#include <math.h>

// CombinedLoss: 0.5*dice + 0.5*CE over [8, 23, 512, 512] f32 logits (NCHW).
// R1-R4 lesson: per-thread "load 23 strided channels -> vmcnt(0) -> compute"
// is latency-serialized (~1.5 TB/s effective). R5: stage tiles in LDS via
// async global_load_lds (width 16), double-buffered, so whole 24KB tiles are
// in flight while the previous tile computes; 3 blocks/CU interleave phases.

#define NC 23
#define HW_SZ 262144               // 512*512
#define NPIX (8 * HW_SZ)           // 2^21
#define TPX 256                    // pixels per tile
#define NTILES (NPIX / TPX)        // 8192
#define NBG 768                    // grid: 3 blocks/CU (LDS-capped)
#define NQ 47                      // inter[23] + denom[23] + ce

__device__ __forceinline__ void gload16(const void* g, void* l) {
    __builtin_amdgcn_global_load_lds(
        (const __attribute__((address_space(1))) unsigned int*)g,
        (__attribute__((address_space(3))) unsigned int*)l, 16, 0, 0);
}

__device__ __forceinline__ float wave_red(float v) {
#pragma unroll
    for (int off = 32; off > 0; off >>= 1) v += __shfl_down(v, off, 64);
    return v;
}

__global__ __launch_bounds__(256) void cl_main(const float* __restrict__ pred,
                                               const int* __restrict__ tgt,
                                               float* __restrict__ partials) {
    // [2 buffers][23 channels + 1 target row][256 px]: 48 KB + red = 48.75 KB
    __shared__ unsigned int lbuf[2][NC + 1][TPX];
    __shared__ float red[4][NQ + 1];

    float inter[NC], denom[NC];
#pragma unroll
    for (int c = 0; c < NC; ++c) { inter[c] = 0.0f; denom[c] = 0.0f; }
    float ce = 0.0f;

    const int bid = blockIdx.x;
    const int lane = threadIdx.x & 63;
    const int wv = threadIdx.x >> 6;

    // Issue the 24 segment loads (1 KB each) for tile tt into buffer buf.
    // Wave wv issues segments [6*wv, 6*wv+6); per-lane global src + linear LDS dest.
    auto issue = [&](int buf, int tt) {
        int b = tt >> 10;                       // image: 1024 tiles per image
        int hw0 = (tt & 1023) << 8;             // pixel offset within image
        const float* pb = pred + (size_t)b * NC * HW_SZ + hw0 + (lane << 2);
#pragma unroll
        for (int k = 0; k < 6; ++k) {
            int j = wv * 6 + k;                 // 0..23, wave-uniform
            if (j < NC) {
                gload16(pb + (size_t)j * HW_SZ, (void*)&lbuf[buf][j][0]);
            } else if (j == NC) {
                gload16(tgt + ((size_t)tt << 8) + (lane << 2), (void*)&lbuf[buf][NC][0]);
            }
        }
    };

    int cur = 0;
    issue(0, bid);
    for (int tt = bid; tt < NTILES; tt += NBG) {
        __syncthreads();                        // drains vmcnt -> buf[cur] ready
        int ttn = tt + NBG;
        if (ttn < NTILES) issue(cur ^ 1, ttn);  // prefetch overlaps compute below

        int px = threadIdx.x;
        float l[NC];
#pragma unroll
        for (int c = 0; c < NC; ++c) l[c] = __uint_as_float(lbuf[cur][c][px]);
        int t = (int)lbuf[cur][NC][px];

        float m = l[0];
#pragma unroll
        for (int c = 1; c < NC; ++c) m = fmaxf(m, l[c]);

        float s = 0.0f, lt = l[0];
#pragma unroll
        for (int c = 0; c < NC; ++c) {
            lt = (c == t) ? l[c] : lt;
            float e = __expf(l[c] - m);
            l[c] = e;
            s += e;
        }
        float rinv = __builtin_amdgcn_rcpf(s);
        ce += m + __logf(s) - lt;

#pragma unroll
        for (int c = 0; c < NC; ++c) {
            float pc = l[c] * rinv;
            bool is_t = (c == t);
            inter[c] += is_t ? pc : 0.0f;
            denom[c] += pc + (is_t ? 1.0f : 0.0f);
        }
        cur ^= 1;
    }

    // Block reduction of 47 quantities -> per-block partials.
#pragma unroll
    for (int c = 0; c < NC; ++c) {
        float v = wave_red(inter[c]);
        if (lane == 0) red[wv][c] = v;
    }
#pragma unroll
    for (int c = 0; c < NC; ++c) {
        float v = wave_red(denom[c]);
        if (lane == 0) red[wv][NC + c] = v;
    }
    {
        float v = wave_red(ce);
        if (lane == 0) red[wv][2 * NC] = v;
    }
    __syncthreads();

    if (threadIdx.x < NQ) {
        float v = red[0][threadIdx.x] + red[1][threadIdx.x] +
                  red[2][threadIdx.x] + red[3][threadIdx.x];
        partials[(size_t)threadIdx.x * NBG + blockIdx.x] = v;
    }
}

__global__ __launch_bounds__(1024) void cl_reduce(const float* __restrict__ partials,
                                                  float* __restrict__ out) {
    __shared__ double res[NQ];
    int lane = threadIdx.x & 63;
    int wv = threadIdx.x >> 6;   // 0..15

    for (int q = wv; q < NQ; q += 16) {
        double acc = 0.0;
        for (int i = lane; i < NBG; i += 64) acc += (double)partials[(size_t)q * NBG + i];
#pragma unroll
        for (int off = 32; off > 0; off >>= 1) acc += __shfl_down(acc, off, 64);
        if (lane == 0) res[q] = acc;
    }
    __syncthreads();

    if (threadIdx.x == 0) {
        const double S = 1e-5;
        double dice_sum = 0.0;
        for (int c = 0; c < NC; ++c) {
            double dice = (2.0 * res[c] + S) / (res[NC + c] + S);
            dice_sum += (1.0 - dice);
        }
        double dice_loss = dice_sum / (double)NC;
        double ce_mean = res[2 * NC] / (double)NPIX;
        out[0] = (float)(0.5 * dice_loss + 0.5 * ce_mean);
    }
}

extern "C" void kernel_launch(void* const* d_in, const int* in_sizes, int n_in,
                              void* d_out, int out_size, void* d_ws, size_t ws_size,
                              hipStream_t stream) {
    const float* pred = (const float*)d_in[0];
    const int* tgt = (const int*)d_in[1];
    float* out = (float*)d_out;
    float* partials = (float*)d_ws;   // NQ * NBG floats = 141 KB

    cl_main<<<NBG, 256, 0, stream>>>(pred, tgt, partials);
    cl_reduce<<<1, 1024, 0, stream>>>(partials, out);
}